// Round 2
// baseline (499.433 us; speedup 1.0000x reference)
//
#include <hip/hip_runtime.h>
#include <cmath>

#define LBINS 401
#define LL (LBINS * LBINS)          // 160801
#define MPAD 160804                 // LL padded to multiple of 4
#define MIN_SEP 2

// accum float indices (ws_f[0..415])
#define ACC_HANY  401   // sum relu(c)*any_i*any_j
#define ACC_HCONV 402   // sum relu(c)*fwd_i*rev_j
#define ACC_SM    403   // sum c (all pairs)
#define ACC_SW    404   // sum c*same (all pairs)
#define ACC_ND    405   // sum c*same over |i-j|==1
#define ACC_FLOATS 416
#define M_OFF ACC_FLOATS
#define ZERO_FLOATS (ACC_FLOATS + MPAD)   // 161220 floats to zero
#define MASKV_OFF ZERO_FLOATS             // float4 mask array (16B aligned: 161220*4 % 16 == 0)

// ---------------------------------------------------------------------------
__global__ void zero_kernel(float* __restrict__ wsf) {
    int t = blockIdx.x * blockDim.x + threadIdx.x;
    if (t < ZERO_FLOATS) wsf[t] = 0.0f;
}

// ---------------------------------------------------------------------------
// prep: per-(b,l) flag byte + float4 mask (any, rev, comp, 0) + near-diagonal
// same-compartment correction ND = sum_{|i-j|=1} c * [comp_i == comp_j].
// ---------------------------------------------------------------------------
__global__ void prep_kernel(const float* __restrict__ cm,
                            const float* __restrict__ logits,
                            const int* __restrict__ ctcf,
                            float* __restrict__ accum,
                            float4* __restrict__ maskv,
                            unsigned char* __restrict__ flags,
                            int B) {
    int t = blockIdx.x * blockDim.x + threadIdx.x;
    int BL = B * LBINS;
    float nd = 0.0f;
    if (t < BL) {
        int b = t / LBINS;
        int i = t - b * LBINS;
        int o = ctcf[t];
        int ci = (logits[2 * t + 1] > logits[2 * t]) ? 1 : 0;
        unsigned char f = 0;
        if (o == 1)  f |= 1;
        if (o == -1) f |= 2;
        if (o != 0)  f |= 4;
        if (ci)      f |= 8;
        flags[t] = f;
        maskv[t] = make_float4(o != 0 ? 1.f : 0.f, o == -1 ? 1.f : 0.f, (float)ci, 0.f);
        const float* row = cm + (size_t)b * LL + (size_t)i * LBINS;
        if (i + 1 < LBINS) {
            int cj = (logits[2 * (t + 1) + 1] > logits[2 * (t + 1)]) ? 1 : 0;
            if (cj == ci) nd += row[i + 1];
        }
        if (i > 0) {
            int cj = (logits[2 * (t - 1) + 1] > logits[2 * (t - 1)]) ? 1 : 0;
            if (cj == ci) nd += row[i - 1];
        }
    }
    #pragma unroll
    for (int off = 32; off > 0; off >>= 1) nd += __shfl_down(nd, off, 64);
    if ((threadIdx.x & 63) == 0) unsafeAtomicAdd(&accum[ACC_ND], nd);
}

// ---------------------------------------------------------------------------
// main: block = (row i, 32-batch group). Thread u owns columns {u, u+128,
// u+256, u+384}. Pure fma inner loop; M accumulated in registers.
// ---------------------------------------------------------------------------
__global__ __launch_bounds__(128)
void main_kernel(const float* __restrict__ cm,
                 const float4* __restrict__ maskv,
                 const unsigned char* __restrict__ flags,
                 float* __restrict__ accum,
                 float* __restrict__ M,
                 int B) {
    int i  = blockIdx.x;
    int b0 = blockIdx.y * 32;
    int bend = min(b0 + 32, B);
    int u = threadIdx.x;

    float Macc[4] = {0.f, 0.f, 0.f, 0.f};
    float HA = 0.f, HC = 0.f, SW = 0.f, SM = 0.f;

    const float* rowp = cm + (size_t)b0 * LL + (size_t)i * LBINS;
    const float4* mrow = maskv + (size_t)b0 * LBINS;
    const unsigned char* fip = flags + (size_t)b0 * LBINS + i;

    for (int b = b0; b < bend; ++b) {
        unsigned char fi = *fip;
        float an = 0.f, rv = 0.f, p1 = 0.f, smr = 0.f;
        #pragma unroll
        for (int m = 0; m < 4; ++m) {
            int j = u + 128 * m;
            if (m < 3 || j < LBINS) {
                float c = rowp[j];
                float4 mk = mrow[j];
                float rc = fmaxf(c, 0.f);
                an = fmaf(rc, mk.x, an);
                rv = fmaf(rc, mk.y, rv);
                p1 = fmaf(c, mk.z, p1);
                smr += c;
                Macc[m] += c;
            }
        }
        float afi = (fi & 4) ? 1.f : 0.f;
        float ffi = (fi & 1) ? 1.f : 0.f;
        HA = fmaf(afi, an, HA);
        HC = fmaf(ffi, rv, HC);
        SW += (fi & 8) ? p1 : (smr - p1);
        SM += smr;
        rowp += LL; mrow += LBINS; fip += LBINS;
    }

    #pragma unroll
    for (int m = 0; m < 4; ++m) {
        int j = u + 128 * m;
        if (m < 3 || j < LBINS)
            unsafeAtomicAdd(&M[i * LBINS + j], Macc[m]);
    }

    #pragma unroll
    for (int off = 32; off > 0; off >>= 1) {
        HA += __shfl_down(HA, off, 64);
        HC += __shfl_down(HC, off, 64);
        SW += __shfl_down(SW, off, 64);
        SM += __shfl_down(SM, off, 64);
    }
    __shared__ float red[2][4];
    int w = u >> 6;
    if ((u & 63) == 0) { red[w][0] = HA; red[w][1] = HC; red[w][2] = SW; red[w][3] = SM; }
    __syncthreads();
    if (u == 0) {
        unsafeAtomicAdd(&accum[ACC_HANY],  red[0][0] + red[1][0]);
        unsafeAtomicAdd(&accum[ACC_HCONV], red[0][1] + red[1][1]);
        unsafeAtomicAdd(&accum[ACC_SW],    red[0][2] + red[1][2]);
        unsafeAtomicAdd(&accum[ACC_SM],    red[0][3] + red[1][3]);
    }
}

// ---------------------------------------------------------------------------
// bins: distance histogram from the 643 KB batch-summed M (L2-resident).
// ---------------------------------------------------------------------------
__global__ __launch_bounds__(128)
void bins_kernel(const float* __restrict__ M, float* __restrict__ accum) {
    __shared__ float lb[LBINS];
    int i = blockIdx.x;
    int u = threadIdx.x;
    for (int s = u; s < LBINS; s += 128) lb[s] = 0.f;
    __syncthreads();
    #pragma unroll
    for (int m = 0; m < 4; ++m) {
        int j = u + 128 * m;
        if (m < 3 || j < LBINS) {
            float v = M[i * LBINS + j];
            int s = i > j ? i - j : j - i;
            atomicAdd(&lb[s], v);
        }
    }
    __syncthreads();
    for (int s = u; s < LBINS; s += 128) unsafeAtomicAdd(&accum[s], lb[s]);
}

// ---------------------------------------------------------------------------
__device__ double block_reduce_d(double v, double* buf) {
    int tid = threadIdx.x;
    buf[tid] = v;
    __syncthreads();
    for (int off = blockDim.x >> 1; off > 0; off >>= 1) {
        if (tid < off) buf[tid] += buf[tid + off];
        __syncthreads();
    }
    double r = buf[0];
    __syncthreads();
    return r;
}

__global__ __launch_bounds__(512)
void final_kernel(const unsigned char* __restrict__ flags,
                  const float* __restrict__ accum,
                  float* __restrict__ out, int B) {
    __shared__ double dred[512];
    int tid = threadIdx.x;
    int lane = tid & 63, w = tid >> 6;   // 8 waves

    // ---- per-batch closed-form counts: wave w handles batches w, w+8, ... ----
    double ncW = 0.0, sameW = 0.0;
    for (int b = w; b < B; b += 8) {
        const unsigned char* bf = flags + (size_t)b * LBINS;
        int n1 = 0, nf = 0, nr = 0, na = 0, adj = 0;
        #pragma unroll
        for (int k = 0; k < 7; ++k) {
            int p = lane + 64 * k;
            if (p < LBINS) {
                int f = bf[p];
                n1 += (f >> 3) & 1; nf += f & 1; nr += (f >> 1) & 1; na += (f >> 2) & 1;
                if (p >= 1) {
                    int f2 = bf[p - 1];
                    adj += 1 - (((f ^ f2) >> 3) & 1);
                }
            }
        }
        #pragma unroll
        for (int off = 32; off > 0; off >>= 1) {
            n1 += __shfl_down(n1, off, 64);
            nf += __shfl_down(nf, off, 64);
            nr += __shfl_down(nr, off, 64);
            na += __shfl_down(na, off, 64);
            adj += __shfl_down(adj, off, 64);
        }
        if (lane == 0) {
            int n0 = LBINS - n1;
            ncW   += (double)na * na - (double)nf * nr;
            sameW += (double)n0 * n0 + (double)n1 * n1 - (double)LBINS - 2.0 * adj;
        }
    }
    double nc_sum   = block_reduce_d(ncW, dred);
    double same_cnt = block_reduce_d(sameW, dred);
    double total_maskf = (double)B * ((double)LL - 3.0 * LBINS + 2.0);
    double diff_cnt = total_maskf - same_cnt;

    // ---- distance-decay regression over 401 bins ----
    float wgt = 0.f, x = 0.f, y = 0.f;
    if (tid < LBINS) {
        float cntB = ((tid == 0) ? (float)LBINS : 2.0f * (float)(LBINS - tid)) * (float)B;
        float mc = accum[tid] / cntB;
        int valid = (tid >= MIN_SEP) && __builtin_isfinite(mc) && (mc > 0.0f);
        wgt = valid ? 1.f : 0.f;
        x = logf(fmaxf((float)tid, 1.0f));
        y = logf((valid ? mc : 1.0f) + 1e-6f);
    }
    double n  = block_reduce_d((double)wgt, dred);
    double Sx = block_reduce_d((double)wgt * x, dred);
    double Sy = block_reduce_d((double)wgt * y, dred);
    double n_safe = fmax(n, 1.0);
    double xm = Sx / n_safe, ym = Sy / n_safe;
    double num = block_reduce_d((double)wgt * ((double)x - xm) * ((double)y - ym), dred);
    double den = block_reduce_d((double)wgt * ((double)x - xm) * ((double)x - xm), dred);

    if (tid == 0) {
        double slope = num / (den + 1e-8);
        float dist_loss = (n >= 5.0) ? (float)((slope + 0.85) * (slope + 0.85)) : 0.0f;

        float ncf = (float)nc_sum;
        float hinge = (accum[ACC_HANY] - accum[ACC_HCONV]) / (ncf + 1e-6f);
        float ctcf_loss = (ncf < 1.0f) ? 0.0f : hinge;

        float within_num  = accum[ACC_SW] - accum[0] - accum[ACC_ND];
        float maskf_num   = accum[ACC_SM] - accum[0] - accum[1];
        float between_num = maskf_num - within_num;
        float within  = within_num  / (float)fmax(same_cnt, 1.0);
        float between = between_num / (float)fmax(diff_cnt, 1.0);
        float ratio = within / (fabsf(between) + 1e-6f);
        float comp_loss = fmaxf(1.5f - ratio, 0.0f);

        float total = 1.0f * dist_loss + 0.5f * ctcf_loss + 0.5f * comp_loss;
        out[0] = dist_loss;
        out[1] = ctcf_loss;
        out[2] = comp_loss;
        out[3] = total;
    }
}

// ---------------------------------------------------------------------------
extern "C" void kernel_launch(void* const* d_in, const int* in_sizes, int n_in,
                              void* d_out, int out_size, void* d_ws, size_t ws_size,
                              hipStream_t stream) {
    const float* cm     = (const float*)d_in[0];   // (B, L, L) fp32
    const float* logits = (const float*)d_in[1];   // (B, L, 2) fp32
    const int*   ctcf   = (const int*)d_in[2];     // (B, L) int32
    float* out = (float*)d_out;

    int total = in_sizes[0];
    int B = total / LL;
    int BL = B * LBINS;

    float* wsf = (float*)d_ws;
    float* accum = wsf;
    float* M = wsf + M_OFF;
    float4* maskv = (float4*)(wsf + MASKV_OFF);
    unsigned char* flags = (unsigned char*)(wsf + MASKV_OFF + (size_t)BL * 4);

    zero_kernel<<<(ZERO_FLOATS + 255) / 256, 256, 0, stream>>>(wsf);
    prep_kernel<<<(BL + 255) / 256, 256, 0, stream>>>(cm, logits, ctcf, accum, maskv, flags, B);
    main_kernel<<<dim3(LBINS, (B + 31) / 32), 128, 0, stream>>>(cm, maskv, flags, accum, M, B);
    bins_kernel<<<LBINS, 128, 0, stream>>>(M, accum);
    final_kernel<<<1, 512, 0, stream>>>(flags, accum, out, B);
}